// Round 1
// baseline (438.077 us; speedup 1.0000x reference)
//
#include <hip/hip_runtime.h>
#include <hip/hip_bf16.h>

#define LEN   16384
#define CIN   256
#define COUT  256
#define NB    8
#define NTAP  9
#define DIL   6
#define PADW  24
#define NSTEP 72           // 9 taps * (256/32) channel chunks

typedef __bf16 bf16x8 __attribute__((ext_vector_type(8)));
typedef float  f32x4  __attribute__((ext_vector_type(4)));
typedef unsigned short u16;
typedef u16 u16x8 __attribute__((ext_vector_type(8)));

// ---------------- ws layout ----------------
// wkt  : NB*NTAP*LEN f32          = 4,718,592 B
// Wb   : NSTEP*256*32 bf16        = 1,179,648 B
// sums : 512 f32 (sum, sqsum)     = 2,048 B
// scb  : 512 f32 (scale, bias)    = 2,048 B
#define WKT_BYTES  (NB*NTAP*LEN*4)
#define WB_BYTES   (NSTEP*256*32*2)
#define SUMS_OFF   (WKT_BYTES + WB_BYTES)
#define SCB_OFF    (SUMS_OFF + 512*4)

// ---------- kernel 1: Gaussian tap-weight table ----------
__global__ __launch_bounds__(256) void k_wk(const float* __restrict__ coords,
                                            float* __restrict__ wkt) {
    int i = blockIdx.x * 256 + threadIdx.x;      // [b][k][l]
    if (i >= NB * NTAP * LEN) return;
    int l = i & (LEN - 1);
    int bk = i >> 14;
    int k = bk % NTAP, b = bk / NTAP;
    const float* cb = coords + (size_t)b * 3 * LEN;
    int lt = l + k * DIL - PADW;
    bool ok = (unsigned)lt < (unsigned)LEN;
    float d2 = 0.f;
#pragma unroll
    for (int j = 0; j < 3; ++j) {
        float cc = cb[j * LEN + l];
        float ct = ok ? cb[j * LEN + lt] : 0.f;
        float d = ct - cc;
        d2 += d * d;
    }
    wkt[i] = expf(-d2 * (1.f / 72.f));
}

// ---------- kernel 2: repack weights W[o][c][k] -> bf16 Wb[s][o][ck] ----------
__global__ __launch_bounds__(256) void k_wb(const float* __restrict__ W,
                                            u16* __restrict__ Wb) {
    int i = blockIdx.x * 256 + threadIdx.x;      // total 72*256*32 = 589824
    if (i >= NSTEP * 256 * 32) return;
    int j = i & 31;
    int o = (i >> 5) & 255;
    int s = i >> 13;
    int k = s >> 3;
    int c = ((s & 7) << 5) + j;
    float v = W[((size_t)o * CIN + c) * NTAP + k];
    unsigned u = __builtin_bit_cast(unsigned, v);
    u += 0x7FFFu + ((u >> 16) & 1u);
    Wb[i] = (u16)(u >> 16);
}

// ---------- kernel 3: the MFMA conv (writes y to d_out, accumulates BN sums) ----------
__global__ __launch_bounds__(256, 2) void k_conv(
    const float* __restrict__ x,       // [8][256][16384]
    const float* __restrict__ wkt,     // [8][9][16384]
    const u16*   __restrict__ Wb,      // [72][256][32] bf16
    float* __restrict__ y,             // [8][256][16384]  (= d_out)
    float* __restrict__ sums)          // [512]
{
    const int lt = blockIdx.x;         // 128 l-tiles
    const int ob = blockIdx.y;         // 2 o-blocks
    const int b  = blockIdx.z;         // 8 batches
    const int l0 = lt * 128;
    const int tid  = threadIdx.x;
    const int lane = tid & 63;
    const int wid  = tid >> 6;
    const int wr = wid >> 1;           // wave o-half (0..1)
    const int wc = wid & 1;            // wave l-half (0..1)

    // padded stride 40 bf16 = 80B: 16B-aligned b128, 2-way banks (free)
    __shared__ u16 As[2][128 * 40];
    __shared__ u16 Bs[2][128 * 40];

    f32x4 acc[4][4] = {};

    const int sl  = tid & 127;         // B-staging row (l within tile)
    const int cg0 = tid >> 7;          // 0..1  (groups cg0, cg0+2)

    bf16x8 aReg[2];
    float  xReg[16];
    float  wkv;

    auto stage_load = [&](int s) {
        const int ktap  = s >> 3;
        const int cbase = (s & 7) << 5;
        const u16* wsrc = Wb + ((size_t)s * 256 + ob * 128) * 32;
#pragma unroll
        for (int i = 0; i < 2; ++i) {
            int idx = i * 256 + tid;
            int o = idx >> 2, kc = idx & 3;
            aReg[i] = *reinterpret_cast<const bf16x8*>(wsrc + o * 32 + kc * 8);
        }
        const int gx = l0 + sl + ktap * DIL - PADW;
        const bool ok = (unsigned)gx < (unsigned)LEN;
        const float* xb = x + (size_t)b * CIN * LEN + gx;
#pragma unroll
        for (int g = 0; g < 2; ++g) {
            int c = cbase + (cg0 + g * 2) * 8;
#pragma unroll
            for (int j = 0; j < 8; ++j)
                xReg[g * 8 + j] = ok ? xb[(size_t)(c + j) * LEN] : 0.f;
        }
        wkv = wkt[((size_t)b * NTAP + ktap) * LEN + l0 + sl];
    };

    auto stage_write = [&](int bufi) {
#pragma unroll
        for (int i = 0; i < 2; ++i) {
            int idx = i * 256 + tid;
            int o = idx >> 2, kc = idx & 3;
            *reinterpret_cast<bf16x8*>(&As[bufi][o * 40 + kc * 8]) = aReg[i];
        }
#pragma unroll
        for (int g = 0; g < 2; ++g) {
            int cg = cg0 + g * 2;
            u16x8 bv;
#pragma unroll
            for (int j = 0; j < 8; ++j) {
                float v = xReg[g * 8 + j] * wkv;
                unsigned u = __builtin_bit_cast(unsigned, v);
                u += 0x7FFFu + ((u >> 16) & 1u);
                bv[j] = (u16)(u >> 16);
            }
            *reinterpret_cast<u16x8*>(&Bs[bufi][sl * 40 + cg * 8]) = bv;
        }
    };

    stage_load(0);
    stage_write(0);
    __syncthreads();

    const int fr  = lane & 15;
    const int kc4 = (lane >> 4) * 8;

    for (int s = 0; s < NSTEP; ++s) {
        const int cur = s & 1;
        if (s < NSTEP - 1) stage_load(s + 1);     // issue next-tile global loads early
        bf16x8 af[4], bfv[4];
        const u16* Ab = &As[cur][(wr * 64 + fr) * 40 + kc4];
        const u16* Bb = &Bs[cur][(wc * 64 + fr) * 40 + kc4];
#pragma unroll
        for (int mi = 0; mi < 4; ++mi)
            af[mi] = *reinterpret_cast<const bf16x8*>(Ab + mi * 16 * 40);
#pragma unroll
        for (int ni = 0; ni < 4; ++ni)
            bfv[ni] = *reinterpret_cast<const bf16x8*>(Bb + ni * 16 * 40);
#pragma unroll
        for (int mi = 0; mi < 4; ++mi)
#pragma unroll
            for (int ni = 0; ni < 4; ++ni)
                acc[mi][ni] = __builtin_amdgcn_mfma_f32_16x16x32_bf16(
                    af[mi], bfv[ni], acc[mi][ni], 0, 0, 0);
        if (s < NSTEP - 1) stage_write(cur ^ 1);  // other buffer: no hazard with reads
        __syncthreads();
    }

    // epilogue: y write + per-channel sum/sqsum
    const int col = lane & 15;
    const int rg  = lane >> 4;
    float* yb = y + ((size_t)b * COUT + ob * 128 + wr * 64) * LEN + l0 + wc * 64;
#pragma unroll
    for (int mi = 0; mi < 4; ++mi) {
#pragma unroll
        for (int r = 0; r < 4; ++r) {
            const int o_loc = mi * 16 + rg * 4 + r;
            float s1 = 0.f, s2 = 0.f;
#pragma unroll
            for (int ni = 0; ni < 4; ++ni) {
                float v = acc[mi][ni][r];
                yb[(size_t)o_loc * LEN + ni * 16 + col] = v;
                s1 += v;
                s2 += v * v;
            }
#pragma unroll
            for (int m = 1; m < 16; m <<= 1) {
                s1 += __shfl_xor(s1, m, 64);
                s2 += __shfl_xor(s2, m, 64);
            }
            if (col == 0) {
                int o = ob * 128 + wr * 64 + o_loc;
                atomicAdd(&sums[o], s1);
                atomicAdd(&sums[COUT + o], s2);
            }
        }
    }
}

// ---------- kernel 4: fold BN stats into per-channel scale/bias ----------
__global__ __launch_bounds__(256) void k_stats(const float* __restrict__ sums,
                                               const float* __restrict__ gamma,
                                               const float* __restrict__ beta,
                                               float* __restrict__ scb) {
    int o = threadIdx.x;
    const float inv_n = 1.f / (float)(NB * LEN);
    float mean = sums[o] * inv_n;
    float var  = sums[COUT + o] * inv_n - mean * mean;
    float sc = gamma[o] * rsqrtf(var + 1e-5f);
    scb[o]        = sc;
    scb[COUT + o] = beta[o] - mean * sc;
}

// ---------- kernel 5: in-place normalize + relu ----------
__global__ __launch_bounds__(256) void k_norm(float* __restrict__ y,
                                              const float* __restrict__ scb) {
    const int total4 = NB * COUT * LEN / 4;
    int i = blockIdx.x * 256 + threadIdx.x;
    for (; i < total4; i += gridDim.x * 256) {
        f32x4 v = reinterpret_cast<f32x4*>(y)[i];
        int o = (i >> 12) & 255;                  // LEN/4 = 4096 per channel row
        float sc = scb[o], bi = scb[COUT + o];
#pragma unroll
        for (int j = 0; j < 4; ++j)
            v[j] = fmaxf(v[j] * sc + bi, 0.f);
        reinterpret_cast<f32x4*>(y)[i] = v;
    }
}

extern "C" void kernel_launch(void* const* d_in, const int* in_sizes, int n_in,
                              void* d_out, int out_size, void* d_ws, size_t ws_size,
                              hipStream_t stream) {
    const float* x      = (const float*)d_in[0];
    const float* coords = (const float*)d_in[1];
    const float* W      = (const float*)d_in[2];
    const float* gamma  = (const float*)d_in[3];
    const float* beta   = (const float*)d_in[4];
    float* out = (float*)d_out;
    char*  ws  = (char*)d_ws;

    float* wkt  = (float*)ws;
    u16*   Wb   = (u16*)(ws + WKT_BYTES);
    float* sums = (float*)(ws + SUMS_OFF);
    float* scb  = (float*)(ws + SCB_OFF);

    hipMemsetAsync(sums, 0, 512 * 4, stream);

    k_wk<<<(NB * NTAP * LEN + 255) / 256, 256, 0, stream>>>(coords, wkt);
    k_wb<<<(NSTEP * 256 * 32 + 255) / 256, 256, 0, stream>>>(W, Wb);

    dim3 g(LEN / 128, 2, NB);
    k_conv<<<g, 256, 0, stream>>>(x, wkt, Wb, out, sums);

    k_stats<<<1, 256, 0, stream>>>(sums, gamma, beta, scb);
    k_norm<<<2048, 256, 0, stream>>>(out, scb);
}